// Round 5
// baseline (1476.700 us; speedup 1.0000x reference)
//
#include <hip/hip_runtime.h>

#define SDIM 4096
#define ALPHA 0.01f
#define WS_LOG 8                      // 64 per-block log partials at [8..72)
#define WS_ARR 128                    // gathered column arrays
#define WS_PART (WS_ARR + 5 * SDIM)   // per-block reduce partials (2*NR floats)
#define NW 2048                       // writer blocks (2 rows each)
#define NR 8192                       // reducer blocks (4x oversubscribed)
#define NTOT (NW + NR)
#define RSTRIDE 2097152               // 2M float4: stride between a thread's 2 pairs

using nfloat4 = __attribute__((ext_vector_type(4))) float;  // native vec for nt-store

// ws layout (floats):
//   [0]                           completion counter (uint), zeroed by k_gather
//   [8..72)                       64 per-block log partials (k_gather)
//   [128 .. 128+5*4096)           c0 | c1 | c3 | u0 | u1
//                                 (u0/u1 = target cols 0/1 SHIFTED +1 so the
//                                  out+1 misalignment becomes aligned float4)
//   [WS_PART .. +8192)            per-block sum_sq partials (reducers)
//   [WS_PART+8192 .. +16384)      per-block sum3 partials   (reducers)

// ---------------------------------------------------------------------------
// Kernel 1: gather columns (with +1 shift on target cols), log partials,
// zero the completion counter (ws may be poisoned between iterations).
// ---------------------------------------------------------------------------
__global__ void k_gather(const float* __restrict__ inp, const float* __restrict__ tgt,
                         float* __restrict__ ws) {
    int n = blockIdx.x * 64 + threadIdx.x;  // 0..4095
    const float* row  = inp + (size_t)n * SDIM;
    const float* trow = tgt + (size_t)n * SDIM;
    float* arr = ws + WS_ARR;

    if (n == 0) ((unsigned*)ws)[0] = 0u;   // reset completion counter

    float v0 = row[0], v1 = row[1], v3 = row[3], v4 = row[4];
    arr[n]            = v0;            // c0
    arr[SDIM + n]     = v1;            // c1
    arr[2 * SDIM + n] = v3;            // c3
    int ns = (n + 1) & (SDIM - 1);     // shifted slot
    arr[3 * SDIM + ns] = trow[0];      // u0[i] = t0[i-1]
    arr[4 * SDIM + ns] = trow[1];      // u1[i] = t1[i-1]

    float lg = logf(v4);
    #pragma unroll
    for (int off = 32; off > 0; off >>= 1) lg += __shfl_down(lg, off);
    if (threadIdx.x == 0) ws[WS_LOG + blockIdx.x] = lg;
}

// ---------------------------------------------------------------------------
// Kernel 2: fused writer + reducer + finisher. 10240 blocks x 256 threads.
//   blocks [0..NW):      cost writer, 2 rows/block, aligned nt float4 stores
//                        (proven ~7 TB/s in round 4). Dispatched first so the
//                        short write phase overlaps the reduce ramp.
//   blocks [NW..NTOT):   reducers, 4x oversubscribed (8192 blocks, 2
//                        float4-pairs per thread) so CU slots freed by
//                        L3-hit-lucky blocks are BACKFILLED — fixes the 48%
//                        occupancy / 2.56 TB/s single-round imbalance.
//   last-done block:     device-scope atomic counter + __threadfence, reduces
//                        the 2*8192 partials + 64 log partials, writes out[0].
// ---------------------------------------------------------------------------
__global__ void __launch_bounds__(256) k_work(const float* __restrict__ inp,
                                              const float* __restrict__ tgt,
                                              float* __restrict__ ws,
                                              float* __restrict__ out) {
    __shared__ float s1[4], s2[4];
    __shared__ int isLast;
    int bid = blockIdx.x;
    int t = threadIdx.x;
    const float* c0 = ws + WS_ARR;
    float* wpart = ws + WS_PART;

    if (bid < NW) {
        // ---- writer role: rows n0, n1; only L2-hot reads (32 KB shared) ----
        int n0 = 2 * bid, n1 = 2 * bid + 1;
        const float* c1 = c0 + SDIM;
        const float4* u04 = (const float4*)(c0 + 3 * SDIM);
        const float4* u14 = (const float4*)(c0 + 4 * SDIM);
        float a00 = c0[n0], b00 = c1[n0];  // wave-uniform scalars
        float a01 = c0[n1], b01 = c1[n1];

        float4 U0[4], U1[4];
        #pragma unroll
        for (int k = 0; k < 4; ++k) {
            U0[k] = u04[k * 256 + t];
            U1[k] = u14[k * 256 + t];
        }

        nfloat4* orow0 = (nfloat4*)(out + (size_t)n0 * SDIM);
        nfloat4* orow1 = (nfloat4*)(out + (size_t)n1 * SDIM);
        #pragma unroll
        for (int k = 0; k < 4; ++k) {
            int j = k * 256 + t;
            float e0, e1;
            nfloat4 v0, v1;
            e0 = a00 - U0[k].x; e1 = b00 - U1[k].x; v0.x = 0.5f * (e0 * e0 + e1 * e1);
            e0 = a00 - U0[k].y; e1 = b00 - U1[k].y; v0.y = 0.5f * (e0 * e0 + e1 * e1);
            e0 = a00 - U0[k].z; e1 = b00 - U1[k].z; v0.z = 0.5f * (e0 * e0 + e1 * e1);
            e0 = a00 - U0[k].w; e1 = b00 - U1[k].w; v0.w = 0.5f * (e0 * e0 + e1 * e1);
            e0 = a01 - U0[k].x; e1 = b01 - U1[k].x; v1.x = 0.5f * (e0 * e0 + e1 * e1);
            e0 = a01 - U0[k].y; e1 = b01 - U1[k].y; v1.y = 0.5f * (e0 * e0 + e1 * e1);
            e0 = a01 - U0[k].z; e1 = b01 - U1[k].z; v1.z = 0.5f * (e0 * e0 + e1 * e1);
            e0 = a01 - U0[k].w; e1 = b01 - U1[k].w; v1.w = 0.5f * (e0 * e0 + e1 * e1);
            if (j == 0) {
                // element 0 of row-range n is cost[n-1][4095] (shifted layout)
                if (n0 == 0) {
                    v0.x = 0.0f;                        // loss slot; finisher overwrites
                } else {
                    float ap = c0[n0 - 1], bp = c1[n0 - 1];
                    e0 = ap - U0[0].x; e1 = bp - U1[0].x;   // U0[0].x = t0[4095]
                    v0.x = 0.5f * (e0 * e0 + e1 * e1);
                }
                // n1 - 1 == n0
                e0 = a00 - U0[0].x; e1 = b00 - U1[0].x;
                v1.x = 0.5f * (e0 * e0 + e1 * e1);
            }
            __builtin_nontemporal_store(v0, &orow0[j]);
            __builtin_nontemporal_store(v1, &orow1[j]);
        }
        if (n1 == SDIM - 1 && t == 255) {
            // tail: out[16M] = cost[4095][4095]
            const float* u0 = c0 + 3 * SDIM;
            const float* u1 = c0 + 4 * SDIM;
            float e0 = a01 - u0[0], e1 = b01 - u1[0];  // u0[0] = t0[4095]
            out[(size_t)SDIM * SDIM] = 0.5f * (e0 * e0 + e1 * e1);
        }
    } else {
        // ---- reducer role: 2 float4-pairs per thread, RSTRIDE apart ----
        int rb = bid - NW;                             // 0..8191
        const float4* inp4 = (const float4*)inp;
        const float4* tgt4 = (const float4*)tgt;
        const float4* c34  = (const float4*)(c0 + 2 * SDIM);
        int base = rb * 256 + t;                       // 0..2097151
        float4 ca = c34[base & 1023];                  // same col for both pairs
        float4 ia = inp4[base],           ta = tgt4[base];
        float4 ib = inp4[base + RSTRIDE], tb = tgt4[base + RSTRIDE];
        float a1 = 0.f, a2 = 0.f, b1 = 0.f, b2 = 0.f;
        float d;
        d = ia.x - ta.x; a1 += d * d;  d = ia.y - ta.y; a1 += d * d;
        d = ia.z - ta.z; a1 += d * d;  d = ia.w - ta.w; a1 += d * d;
        d = ca.x - ta.x; a2 += d * d;  d = ca.y - ta.y; a2 += d * d;
        d = ca.z - ta.z; a2 += d * d;  d = ca.w - ta.w; a2 += d * d;
        d = ib.x - tb.x; b1 += d * d;  d = ib.y - tb.y; b1 += d * d;
        d = ib.z - tb.z; b1 += d * d;  d = ib.w - tb.w; b1 += d * d;
        d = ca.x - tb.x; b2 += d * d;  d = ca.y - tb.y; b2 += d * d;
        d = ca.z - tb.z; b2 += d * d;  d = ca.w - tb.w; b2 += d * d;
        a1 += b1; a2 += b2;
        #pragma unroll
        for (int off = 32; off > 0; off >>= 1) {
            a1 += __shfl_down(a1, off);
            a2 += __shfl_down(a2, off);
        }
        int wave = t >> 6;
        if ((t & 63) == 0) { s1[wave] = a1; s2[wave] = a2; }
        __syncthreads();
        if (t == 0) {
            wpart[rb]      = s1[0] + s1[1] + s1[2] + s1[3];
            wpart[NR + rb] = s2[0] + s2[1] + s2[2] + s2[3];
        }
    }

    // ---- completion protocol: last block does the final reduction ----
    __threadfence();                                   // release partials/out
    if (t == 0) {
        unsigned done = atomicAdd((unsigned*)ws, 1u);
        isLast = (done == NTOT - 1) ? 1 : 0;
    }
    __syncthreads();
    if (isLast) {
        __threadfence();                               // acquire: see all partials
        float a1 = 0.0f, a2 = 0.0f;
        for (int i = t; i < NR; i += 256) {
            a1 += wpart[i];
            a2 += wpart[NR + i];
        }
        #pragma unroll
        for (int off = 32; off > 0; off >>= 1) {
            a1 += __shfl_down(a1, off);
            a2 += __shfl_down(a2, off);
        }
        int wave = t >> 6;
        __syncthreads();                               // s1/s2 reuse
        if ((t & 63) == 0) { s1[wave] = a1; s2[wave] = a2; }
        __syncthreads();
        if (t == 0) {
            float sum_sq = s1[0] + s1[1] + s1[2] + s1[3];
            float sum3   = s2[0] + s2[1] + s2[2] + s2[3];
            float slog = 0.0f;
            #pragma unroll
            for (int i = 0; i < 64; ++i) slog += ws[WS_LOG + i];
            out[0] = ALPHA * sum_sq - (float)SDIM * slog
                   + sum3 * (1.0f / ((float)SDIM * (float)SDIM));
        }
    }
}

extern "C" void kernel_launch(void* const* d_in, const int* in_sizes, int n_in,
                              void* d_out, int out_size, void* d_ws, size_t ws_size,
                              hipStream_t stream) {
    const float* inp = (const float*)d_in[0];
    const float* tgt = (const float*)d_in[1];
    float* out = (float*)d_out;
    float* ws  = (float*)d_ws;

    k_gather<<<64, 64, 0, stream>>>(inp, tgt, ws);
    k_work<<<NTOT, 256, 0, stream>>>(inp, tgt, ws, out);
}

// Round 6
// 183.929 us; speedup vs baseline: 8.0286x; 8.0286x over previous
//
#include <hip/hip_runtime.h>

#define SDIM 4096
#define ALPHA 0.01f
#define WS_LOG 8                      // 64 per-block log partials at [8..72)
#define WS_ARR 128                    // gathered column arrays
#define WS_PART (WS_ARR + 5 * SDIM)   // per-block reduce partials (2*NR floats)
#define NW 2048                       // writer blocks (2 rows each)
#define NR 8192                       // reducer blocks (4x oversubscribed)
#define RSTRIDE 2097152               // 2M float4: stride between a thread's 2 pairs

using nfloat4 = __attribute__((ext_vector_type(4))) float;  // native vec for nt-store

// ws layout (floats):
//   [8..72)                       64 per-block log partials (k_gather)
//   [128 .. 128+5*4096)           c0 | c1 | c3 | u0 | u1
//                                 (u0/u1 = target cols 0/1 SHIFTED +1 so the
//                                  out+1 misalignment becomes aligned float4)
//   [WS_PART .. +8192)            per-block sum_sq partials (k_reduce)
//   [WS_PART+8192 .. +16384)      per-block sum3 partials   (k_reduce)
// (r5 verified this 8192-partial layout fits ws and is correct.)

// ---------------------------------------------------------------------------
// Kernel 1: gather columns (with +1 shift on target cols), log partials.
// ---------------------------------------------------------------------------
__global__ void k_gather(const float* __restrict__ inp, const float* __restrict__ tgt,
                         float* __restrict__ ws) {
    int n = blockIdx.x * 64 + threadIdx.x;  // 0..4095
    const float* row  = inp + (size_t)n * SDIM;
    const float* trow = tgt + (size_t)n * SDIM;
    float* arr = ws + WS_ARR;

    float v0 = row[0], v1 = row[1], v3 = row[3], v4 = row[4];
    arr[n]            = v0;            // c0
    arr[SDIM + n]     = v1;            // c1
    arr[2 * SDIM + n] = v3;            // c3
    int ns = (n + 1) & (SDIM - 1);     // shifted slot
    arr[3 * SDIM + ns] = trow[0];      // u0[i] = t0[i-1]
    arr[4 * SDIM + ns] = trow[1];      // u1[i] = t1[i-1]

    float lg = logf(v4);
    #pragma unroll
    for (int off = 32; off > 0; off >>= 1) lg += __shfl_down(lg, off);
    if (threadIdx.x == 0) ws[WS_LOG + blockIdx.x] = lg;
}

// ---------------------------------------------------------------------------
// Kernel 2: pure cost writer (proven ~9 us / ~7 TB/s in round 4).
// 2048 blocks x 256 threads, 2 rows/block, aligned nontemporal float4 stores,
// only L2-hot reads (32 KB shared across all blocks).
// ---------------------------------------------------------------------------
__global__ void __launch_bounds__(256) k_write(const float* __restrict__ ws,
                                               float* __restrict__ out) {
    int b = blockIdx.x;                // 0..2047
    int t = threadIdx.x;
    int n0 = 2 * b, n1 = 2 * b + 1;
    const float* c0 = ws + WS_ARR;
    const float* c1 = c0 + SDIM;
    const float4* u04 = (const float4*)(c0 + 3 * SDIM);
    const float4* u14 = (const float4*)(c0 + 4 * SDIM);

    float a00 = c0[n0], b00 = c1[n0];  // wave-uniform scalars
    float a01 = c0[n1], b01 = c1[n1];

    float4 U0[4], U1[4];
    #pragma unroll
    for (int k = 0; k < 4; ++k) {
        U0[k] = u04[k * 256 + t];
        U1[k] = u14[k * 256 + t];
    }

    nfloat4* orow0 = (nfloat4*)(out + (size_t)n0 * SDIM);
    nfloat4* orow1 = (nfloat4*)(out + (size_t)n1 * SDIM);
    #pragma unroll
    for (int k = 0; k < 4; ++k) {
        int j = k * 256 + t;
        float e0, e1;
        nfloat4 v0, v1;
        e0 = a00 - U0[k].x; e1 = b00 - U1[k].x; v0.x = 0.5f * (e0 * e0 + e1 * e1);
        e0 = a00 - U0[k].y; e1 = b00 - U1[k].y; v0.y = 0.5f * (e0 * e0 + e1 * e1);
        e0 = a00 - U0[k].z; e1 = b00 - U1[k].z; v0.z = 0.5f * (e0 * e0 + e1 * e1);
        e0 = a00 - U0[k].w; e1 = b00 - U1[k].w; v0.w = 0.5f * (e0 * e0 + e1 * e1);
        e0 = a01 - U0[k].x; e1 = b01 - U1[k].x; v1.x = 0.5f * (e0 * e0 + e1 * e1);
        e0 = a01 - U0[k].y; e1 = b01 - U1[k].y; v1.y = 0.5f * (e0 * e0 + e1 * e1);
        e0 = a01 - U0[k].z; e1 = b01 - U1[k].z; v1.z = 0.5f * (e0 * e0 + e1 * e1);
        e0 = a01 - U0[k].w; e1 = b01 - U1[k].w; v1.w = 0.5f * (e0 * e0 + e1 * e1);
        if (j == 0) {
            // element 0 of row-range n is cost[n-1][4095] (shifted layout)
            if (n0 == 0) {
                v0.x = 0.0f;                       // loss slot; k_final overwrites
            } else {
                float ap = c0[n0 - 1], bp = c1[n0 - 1];
                e0 = ap - U0[0].x; e1 = bp - U1[0].x;   // U0[0].x = t0[4095]
                v0.x = 0.5f * (e0 * e0 + e1 * e1);
            }
            // n1 - 1 == n0
            e0 = a00 - U0[0].x; e1 = b00 - U1[0].x;
            v1.x = 0.5f * (e0 * e0 + e1 * e1);
        }
        __builtin_nontemporal_store(v0, &orow0[j]);
        __builtin_nontemporal_store(v1, &orow1[j]);
    }
    if (n1 == SDIM - 1 && t == 255) {
        // tail: out[16M] = cost[4095][4095]
        const float* u0 = c0 + 3 * SDIM;
        const float* u1 = c0 + 4 * SDIM;
        float e0 = a01 - u0[0], e1 = b01 - u1[0];  // u0[0] = t0[4095]
        out[(size_t)SDIM * SDIM] = 0.5f * (e0 * e0 + e1 * e1);
    }
}

// ---------------------------------------------------------------------------
// Kernel 3: streaming reduction, 8192 blocks x 256 threads (4 residency
// rounds): blocks freed by L3-hit-lucky early finishers are backfilled, so
// cache-hit variance no longer turns into idle CUs (round-4 showed 48%
// occupancy with an exactly-one-round grid; round-5 showed 88% at 4x).
//   sum_sq = sum (inp-tgt)^2, sum3 = sum (c3[col]-tgt)^2
// ---------------------------------------------------------------------------
__global__ void __launch_bounds__(256) k_reduce(const float* __restrict__ inp,
                                                const float* __restrict__ tgt,
                                                const float* __restrict__ ws,
                                                float* __restrict__ wpart) {
    __shared__ float s1[4], s2[4];
    int rb = blockIdx.x;                           // 0..8191
    int t = threadIdx.x;
    const float* c0 = ws + WS_ARR;
    const float4* inp4 = (const float4*)inp;
    const float4* tgt4 = (const float4*)tgt;
    const float4* c34  = (const float4*)(c0 + 2 * SDIM);
    int base = rb * 256 + t;                       // 0..2097151 (float4 idx)
    // (base + RSTRIDE) & 1023 == base & 1023 -> c3 fragment shared by both pairs
    float4 ca = c34[base & 1023];
    float4 ia = inp4[base],           ta = tgt4[base];
    float4 ib = inp4[base + RSTRIDE], tb = tgt4[base + RSTRIDE];
    float a1 = 0.f, a2 = 0.f, b1 = 0.f, b2 = 0.f;
    float d;
    d = ia.x - ta.x; a1 += d * d;  d = ia.y - ta.y; a1 += d * d;
    d = ia.z - ta.z; a1 += d * d;  d = ia.w - ta.w; a1 += d * d;
    d = ca.x - ta.x; a2 += d * d;  d = ca.y - ta.y; a2 += d * d;
    d = ca.z - ta.z; a2 += d * d;  d = ca.w - ta.w; a2 += d * d;
    d = ib.x - tb.x; b1 += d * d;  d = ib.y - tb.y; b1 += d * d;
    d = ib.z - tb.z; b1 += d * d;  d = ib.w - tb.w; b1 += d * d;
    d = ca.x - tb.x; b2 += d * d;  d = ca.y - tb.y; b2 += d * d;
    d = ca.z - tb.z; b2 += d * d;  d = ca.w - tb.w; b2 += d * d;
    a1 += b1; a2 += b2;
    #pragma unroll
    for (int off = 32; off > 0; off >>= 1) {
        a1 += __shfl_down(a1, off);
        a2 += __shfl_down(a2, off);
    }
    int wave = t >> 6;
    if ((t & 63) == 0) { s1[wave] = a1; s2[wave] = a2; }
    __syncthreads();
    if (t == 0) {
        wpart[rb]      = s1[0] + s1[1] + s1[2] + s1[3];
        wpart[NR + rb] = s2[0] + s2[1] + s2[2] + s2[3];
    }
}

// ---------------------------------------------------------------------------
// Kernel 4: reduce 2*8192 partials + 64 log partials, emit loss.
//   loss = ALPHA * sum_sq - S * sum_log + sum3 / (S*S)
// ---------------------------------------------------------------------------
__global__ void k_final(const float* __restrict__ ws, float* __restrict__ out) {
    __shared__ float s1[4], s2[4];
    float a1 = 0.0f, a2 = 0.0f;
    const float* wpart = ws + WS_PART;
    for (int i = threadIdx.x; i < NR; i += 256) {
        a1 += wpart[i];
        a2 += wpart[NR + i];
    }
    #pragma unroll
    for (int off = 32; off > 0; off >>= 1) {
        a1 += __shfl_down(a1, off);
        a2 += __shfl_down(a2, off);
    }
    int wave = threadIdx.x >> 6;
    if ((threadIdx.x & 63) == 0) { s1[wave] = a1; s2[wave] = a2; }
    __syncthreads();
    if (threadIdx.x == 0) {
        float sum_sq = s1[0] + s1[1] + s1[2] + s1[3];
        float sum3   = s2[0] + s2[1] + s2[2] + s2[3];
        float slog = 0.0f;
        #pragma unroll
        for (int i = 0; i < 64; ++i) slog += ws[WS_LOG + i];
        out[0] = ALPHA * sum_sq - (float)SDIM * slog
               + sum3 * (1.0f / ((float)SDIM * (float)SDIM));
    }
}

extern "C" void kernel_launch(void* const* d_in, const int* in_sizes, int n_in,
                              void* d_out, int out_size, void* d_ws, size_t ws_size,
                              hipStream_t stream) {
    const float* inp = (const float*)d_in[0];
    const float* tgt = (const float*)d_in[1];
    float* out = (float*)d_out;
    float* ws  = (float*)d_ws;

    k_gather<<<64, 64, 0, stream>>>(inp, tgt, ws);
    k_write<<<NW, 256, 0, stream>>>(ws, out);
    k_reduce<<<NR, 256, 0, stream>>>(inp, tgt, ws, ws + WS_PART);
    k_final<<<1, 256, 0, stream>>>(ws, out);
}

// Round 7
// 174.639 us; speedup vs baseline: 8.4557x; 1.0532x over previous
//
#include <hip/hip_runtime.h>

#define SDIM 4096
#define ALPHA 0.01f
#define WS_LOG 8                      // 64 per-block log partials at [8..72)
#define WS_ARR 128                    // gathered column arrays
#define WS_PART (WS_ARR + 5 * SDIM)   // per-block reduce partials (2*NR floats)
#define NW 2048                       // writer blocks (2 rows each)
#define NR 8192                       // reducer blocks
#define RSTRIDE 2097152               // 2M float4: stride between a thread's 2 pairs

using nfloat4 = __attribute__((ext_vector_type(4))) float;  // native vec for nt-store

// ws layout (floats):
//   [8..72)                       64 per-block log partials (k_gather)
//   [128 .. 128+5*4096)           c0 | c1 | c3 | u0 | u1
//                                 (u0/u1 = target cols 0/1 SHIFTED +1 so the
//                                  out+1 misalignment becomes aligned float4)
//   [WS_PART .. +8192)            per-block sum_sq partials (k_reduce)
//   [WS_PART+8192 .. +16384)      per-block sum3 partials   (k_reduce)

// ---------------------------------------------------------------------------
// Kernel 1: gather columns (with +1 shift on target cols), log partials.
// ---------------------------------------------------------------------------
__global__ void k_gather(const float* __restrict__ inp, const float* __restrict__ tgt,
                         float* __restrict__ ws) {
    int n = blockIdx.x * 64 + threadIdx.x;  // 0..4095
    const float* row  = inp + (size_t)n * SDIM;
    const float* trow = tgt + (size_t)n * SDIM;
    float* arr = ws + WS_ARR;

    float v0 = row[0], v1 = row[1], v3 = row[3], v4 = row[4];
    arr[n]            = v0;            // c0
    arr[SDIM + n]     = v1;            // c1
    arr[2 * SDIM + n] = v3;            // c3
    int ns = (n + 1) & (SDIM - 1);     // shifted slot
    arr[3 * SDIM + ns] = trow[0];      // u0[i] = t0[i-1]
    arr[4 * SDIM + ns] = trow[1];      // u1[i] = t1[i-1]

    float lg = logf(v4);
    #pragma unroll
    for (int off = 32; off > 0; off >>= 1) lg += __shfl_down(lg, off);
    if (threadIdx.x == 0) ws[WS_LOG + blockIdx.x] = lg;
}

// ---------------------------------------------------------------------------
// Kernel 2: streaming reduction (RUNS BEFORE THE WRITER so the 64 MB cost
// writeback does not share the fabric with this kernel's reads).
// 8192 blocks x 256 threads, 2 float4-pairs per thread.
//   sum_sq = sum (inp-tgt)^2, sum3 = sum (c3[col]-tgt)^2
// ---------------------------------------------------------------------------
__global__ void __launch_bounds__(256) k_reduce(const float* __restrict__ inp,
                                                const float* __restrict__ tgt,
                                                const float* __restrict__ ws,
                                                float* __restrict__ wpart) {
    __shared__ float s1[4], s2[4];
    int rb = blockIdx.x;                           // 0..8191
    int t = threadIdx.x;
    const float* c0 = ws + WS_ARR;
    const float4* inp4 = (const float4*)inp;
    const float4* tgt4 = (const float4*)tgt;
    const float4* c34  = (const float4*)(c0 + 2 * SDIM);
    int base = rb * 256 + t;                       // 0..2097151 (float4 idx)
    // (base + RSTRIDE) & 1023 == base & 1023 -> c3 fragment shared by both pairs
    float4 ca = c34[base & 1023];
    float4 ia = inp4[base],           ta = tgt4[base];
    float4 ib = inp4[base + RSTRIDE], tb = tgt4[base + RSTRIDE];
    float a1 = 0.f, a2 = 0.f, b1 = 0.f, b2 = 0.f;
    float d;
    d = ia.x - ta.x; a1 += d * d;  d = ia.y - ta.y; a1 += d * d;
    d = ia.z - ta.z; a1 += d * d;  d = ia.w - ta.w; a1 += d * d;
    d = ca.x - ta.x; a2 += d * d;  d = ca.y - ta.y; a2 += d * d;
    d = ca.z - ta.z; a2 += d * d;  d = ca.w - ta.w; a2 += d * d;
    d = ib.x - tb.x; b1 += d * d;  d = ib.y - tb.y; b1 += d * d;
    d = ib.z - tb.z; b1 += d * d;  d = ib.w - tb.w; b1 += d * d;
    d = ca.x - tb.x; b2 += d * d;  d = ca.y - tb.y; b2 += d * d;
    d = ca.z - tb.z; b2 += d * d;  d = ca.w - tb.w; b2 += d * d;
    a1 += b1; a2 += b2;
    #pragma unroll
    for (int off = 32; off > 0; off >>= 1) {
        a1 += __shfl_down(a1, off);
        a2 += __shfl_down(a2, off);
    }
    int wave = t >> 6;
    if ((t & 63) == 0) { s1[wave] = a1; s2[wave] = a2; }
    __syncthreads();
    if (t == 0) {
        wpart[rb]      = s1[0] + s1[1] + s1[2] + s1[3];
        wpart[NR + rb] = s2[0] + s2[1] + s2[2] + s2[3];
    }
}

// ---------------------------------------------------------------------------
// Kernel 3: pure cost writer. 2048 blocks x 256 threads, 2 rows/block,
// aligned nontemporal float4 stores, only L2-hot reads (32 KB shared).
// Its HBM writeback drain overlaps k_final / graph end, not k_reduce.
// ---------------------------------------------------------------------------
__global__ void __launch_bounds__(256) k_write(const float* __restrict__ ws,
                                               float* __restrict__ out) {
    int b = blockIdx.x;                // 0..2047
    int t = threadIdx.x;
    int n0 = 2 * b, n1 = 2 * b + 1;
    const float* c0 = ws + WS_ARR;
    const float* c1 = c0 + SDIM;
    const float4* u04 = (const float4*)(c0 + 3 * SDIM);
    const float4* u14 = (const float4*)(c0 + 4 * SDIM);

    float a00 = c0[n0], b00 = c1[n0];  // wave-uniform scalars
    float a01 = c0[n1], b01 = c1[n1];

    float4 U0[4], U1[4];
    #pragma unroll
    for (int k = 0; k < 4; ++k) {
        U0[k] = u04[k * 256 + t];
        U1[k] = u14[k * 256 + t];
    }

    nfloat4* orow0 = (nfloat4*)(out + (size_t)n0 * SDIM);
    nfloat4* orow1 = (nfloat4*)(out + (size_t)n1 * SDIM);
    #pragma unroll
    for (int k = 0; k < 4; ++k) {
        int j = k * 256 + t;
        float e0, e1;
        nfloat4 v0, v1;
        e0 = a00 - U0[k].x; e1 = b00 - U1[k].x; v0.x = 0.5f * (e0 * e0 + e1 * e1);
        e0 = a00 - U0[k].y; e1 = b00 - U1[k].y; v0.y = 0.5f * (e0 * e0 + e1 * e1);
        e0 = a00 - U0[k].z; e1 = b00 - U1[k].z; v0.z = 0.5f * (e0 * e0 + e1 * e1);
        e0 = a00 - U0[k].w; e1 = b00 - U1[k].w; v0.w = 0.5f * (e0 * e0 + e1 * e1);
        e0 = a01 - U0[k].x; e1 = b01 - U1[k].x; v1.x = 0.5f * (e0 * e0 + e1 * e1);
        e0 = a01 - U0[k].y; e1 = b01 - U1[k].y; v1.y = 0.5f * (e0 * e0 + e1 * e1);
        e0 = a01 - U0[k].z; e1 = b01 - U1[k].z; v1.z = 0.5f * (e0 * e0 + e1 * e1);
        e0 = a01 - U0[k].w; e1 = b01 - U1[k].w; v1.w = 0.5f * (e0 * e0 + e1 * e1);
        if (j == 0) {
            // element 0 of row-range n is cost[n-1][4095] (shifted layout)
            if (n0 == 0) {
                v0.x = 0.0f;                       // loss slot; k_final overwrites
            } else {
                float ap = c0[n0 - 1], bp = c1[n0 - 1];
                e0 = ap - U0[0].x; e1 = bp - U1[0].x;   // U0[0].x = t0[4095]
                v0.x = 0.5f * (e0 * e0 + e1 * e1);
            }
            // n1 - 1 == n0
            e0 = a00 - U0[0].x; e1 = b00 - U1[0].x;
            v1.x = 0.5f * (e0 * e0 + e1 * e1);
        }
        __builtin_nontemporal_store(v0, &orow0[j]);
        __builtin_nontemporal_store(v1, &orow1[j]);
    }
    if (n1 == SDIM - 1 && t == 255) {
        // tail: out[16M] = cost[4095][4095]
        const float* u0 = c0 + 3 * SDIM;
        const float* u1 = c0 + 4 * SDIM;
        float e0 = a01 - u0[0], e1 = b01 - u1[0];  // u0[0] = t0[4095]
        out[(size_t)SDIM * SDIM] = 0.5f * (e0 * e0 + e1 * e1);
    }
}

// ---------------------------------------------------------------------------
// Kernel 4: reduce 2*8192 partials + 64 log partials, emit loss.
// 1024 threads + float4 loads: the 64 KB partial array is consumed in one
// latency round (the old 256-thread scalar version serialized ~32 rounds in
// a single block — a hidden straggler).
//   loss = ALPHA * sum_sq - S * sum_log + sum3 / (S*S)
// ---------------------------------------------------------------------------
__global__ void __launch_bounds__(1024) k_final(const float* __restrict__ ws,
                                                float* __restrict__ out) {
    __shared__ float s1[16], s2[16];
    int t = threadIdx.x;
    const float4* w1 = (const float4*)(ws + WS_PART);        // 2048 float4
    const float4* w2 = (const float4*)(ws + WS_PART + NR);   // 2048 float4
    float4 p = w1[t], q = w1[t + 1024];
    float4 r = w2[t], s = w2[t + 1024];
    float a1 = (p.x + p.y) + (p.z + p.w) + (q.x + q.y) + (q.z + q.w);
    float a2 = (r.x + r.y) + (r.z + r.w) + (s.x + s.y) + (s.z + s.w);
    #pragma unroll
    for (int off = 32; off > 0; off >>= 1) {
        a1 += __shfl_down(a1, off);
        a2 += __shfl_down(a2, off);
    }
    int wave = t >> 6;
    if ((t & 63) == 0) { s1[wave] = a1; s2[wave] = a2; }
    __syncthreads();
    if (t == 0) {
        float sum_sq = 0.0f, sum3 = 0.0f;
        #pragma unroll
        for (int i = 0; i < 16; ++i) { sum_sq += s1[i]; sum3 += s2[i]; }
        float slog = 0.0f;
        #pragma unroll
        for (int i = 0; i < 64; ++i) slog += ws[WS_LOG + i];
        out[0] = ALPHA * sum_sq - (float)SDIM * slog
               + sum3 * (1.0f / ((float)SDIM * (float)SDIM));
    }
}

extern "C" void kernel_launch(void* const* d_in, const int* in_sizes, int n_in,
                              void* d_out, int out_size, void* d_ws, size_t ws_size,
                              hipStream_t stream) {
    const float* inp = (const float*)d_in[0];
    const float* tgt = (const float*)d_in[1];
    float* out = (float*)d_out;
    float* ws  = (float*)d_ws;

    k_gather<<<64, 64, 0, stream>>>(inp, tgt, ws);
    k_reduce<<<NR, 256, 0, stream>>>(inp, tgt, ws, ws + WS_PART);
    k_write<<<NW, 256, 0, stream>>>(ws, out);
    k_final<<<1, 1024, 0, stream>>>(ws, out);
}

// Round 8
// 171.456 us; speedup vs baseline: 8.6127x; 1.0186x over previous
//
#include <hip/hip_runtime.h>

#define SDIM 4096
#define ALPHA 0.01f
#define WS_LOG 8                      // 64 per-block log partials at [8..72)
#define WS_ARR 128                    // gathered column arrays
#define WS_PART (WS_ARR + 5 * SDIM)   // per-block reduce partials (2*NR floats)
#define NW 2048                       // writer blocks (2 rows each)
#define NR 8192                       // reducer blocks
#define RSTRIDE 2097152               // 2M float4: stride between a thread's 2 pairs

using nfloat4 = __attribute__((ext_vector_type(4))) float;  // native vec for nt-store

// ws layout (floats):
//   [8..72)                       64 per-block log partials (k_gather)
//   [128 .. 128+5*4096)           c0 | c1 | c3 | u0 | u1
//                                 (u0/u1 = target cols 0/1 SHIFTED +1 so the
//                                  out+1 misalignment becomes aligned float4)
//   [WS_PART .. +8192)            per-block sum_sq partials (k_reduce)
//   [WS_PART+8192 .. +16384)      per-block sum3 partials   (k_reduce)

// ---------------------------------------------------------------------------
// Kernel 1: gather columns (with +1 shift on target cols), log partials.
// ---------------------------------------------------------------------------
__global__ void k_gather(const float* __restrict__ inp, const float* __restrict__ tgt,
                         float* __restrict__ ws) {
    int n = blockIdx.x * 64 + threadIdx.x;  // 0..4095
    const float* row  = inp + (size_t)n * SDIM;
    const float* trow = tgt + (size_t)n * SDIM;
    float* arr = ws + WS_ARR;

    float v0 = row[0], v1 = row[1], v3 = row[3], v4 = row[4];
    arr[n]            = v0;            // c0
    arr[SDIM + n]     = v1;            // c1
    arr[2 * SDIM + n] = v3;            // c3
    int ns = (n + 1) & (SDIM - 1);     // shifted slot
    arr[3 * SDIM + ns] = trow[0];      // u0[i] = t0[i-1]
    arr[4 * SDIM + ns] = trow[1];      // u1[i] = t1[i-1]

    float lg = logf(v4);
    #pragma unroll
    for (int off = 32; off > 0; off >>= 1) lg += __shfl_down(lg, off);
    if (threadIdx.x == 0) ws[WS_LOG + blockIdx.x] = lg;
}

// ---------------------------------------------------------------------------
// Kernel 2: streaming reduction (runs before the writer so the 64 MB cost
// writeback does not share the fabric with this kernel's reads).
// 8192 blocks x 256 threads, 2 float4-pairs per thread.
//   sum_sq = sum (inp-tgt)^2, sum3 = sum (c3[col]-tgt)^2
// (Invariant at 46-50 us across 3 structures: MLP depth, occupancy and
//  ordering all move it <=8%; FETCH pinned at 65.5 MB.)
// ---------------------------------------------------------------------------
__global__ void __launch_bounds__(256) k_reduce(const float* __restrict__ inp,
                                                const float* __restrict__ tgt,
                                                const float* __restrict__ ws,
                                                float* __restrict__ wpart) {
    __shared__ float s1[4], s2[4];
    int rb = blockIdx.x;                           // 0..8191
    int t = threadIdx.x;
    const float* c0 = ws + WS_ARR;
    const float4* inp4 = (const float4*)inp;
    const float4* tgt4 = (const float4*)tgt;
    const float4* c34  = (const float4*)(c0 + 2 * SDIM);
    int base = rb * 256 + t;                       // 0..2097151 (float4 idx)
    // (base + RSTRIDE) & 1023 == base & 1023 -> c3 fragment shared by both pairs
    float4 ca = c34[base & 1023];
    float4 ia = inp4[base],           ta = tgt4[base];
    float4 ib = inp4[base + RSTRIDE], tb = tgt4[base + RSTRIDE];
    float a1 = 0.f, a2 = 0.f, b1 = 0.f, b2 = 0.f;
    float d;
    d = ia.x - ta.x; a1 += d * d;  d = ia.y - ta.y; a1 += d * d;
    d = ia.z - ta.z; a1 += d * d;  d = ia.w - ta.w; a1 += d * d;
    d = ca.x - ta.x; a2 += d * d;  d = ca.y - ta.y; a2 += d * d;
    d = ca.z - ta.z; a2 += d * d;  d = ca.w - ta.w; a2 += d * d;
    d = ib.x - tb.x; b1 += d * d;  d = ib.y - tb.y; b1 += d * d;
    d = ib.z - tb.z; b1 += d * d;  d = ib.w - tb.w; b1 += d * d;
    d = ca.x - tb.x; b2 += d * d;  d = ca.y - tb.y; b2 += d * d;
    d = ca.z - tb.z; b2 += d * d;  d = ca.w - tb.w; b2 += d * d;
    a1 += b1; a2 += b2;
    #pragma unroll
    for (int off = 32; off > 0; off >>= 1) {
        a1 += __shfl_down(a1, off);
        a2 += __shfl_down(a2, off);
    }
    int wave = t >> 6;
    if ((t & 63) == 0) { s1[wave] = a1; s2[wave] = a2; }
    __syncthreads();
    if (t == 0) {
        wpart[rb]      = s1[0] + s1[1] + s1[2] + s1[3];
        wpart[NR + rb] = s2[0] + s2[1] + s2[2] + s2[3];
    }
}

// ---------------------------------------------------------------------------
// Kernel 3: cost writer + finisher, 2049 blocks x 256 threads.
//   blocks [0..NW): writer, 2 rows/block, aligned nontemporal float4 stores.
//   block NW:       final reduction of wpart (visible via the k_reduce kernel
//                   boundary — stream order, NO fences needed) + log partials,
//                   writes out[0]. Writer block 0 skips out[0] (scalar .y/.z/.w
//                   stores) so there is no race on the loss slot.
// Merging k_final here removes one ~5-10 us kernel launch from the timed path.
// ---------------------------------------------------------------------------
__global__ void __launch_bounds__(256) k_writefin(const float* __restrict__ ws,
                                                  float* __restrict__ out) {
    int b = blockIdx.x;                // 0..2048
    int t = threadIdx.x;
    const float* c0 = ws + WS_ARR;

    if (b == NW) {
        // ---- finisher block: reduce 2*8192 partials + 64 log partials ----
        __shared__ float f1[4], f2[4];
        const float4* w1 = (const float4*)(ws + WS_PART);        // 2048 float4
        const float4* w2 = (const float4*)(ws + WS_PART + NR);   // 2048 float4
        float a1 = 0.f, a2 = 0.f;
        #pragma unroll
        for (int k = 0; k < 8; ++k) {
            float4 p = w1[t + k * 256];
            float4 q = w2[t + k * 256];
            a1 += (p.x + p.y) + (p.z + p.w);
            a2 += (q.x + q.y) + (q.z + q.w);
        }
        #pragma unroll
        for (int off = 32; off > 0; off >>= 1) {
            a1 += __shfl_down(a1, off);
            a2 += __shfl_down(a2, off);
        }
        int wave = t >> 6;
        if ((t & 63) == 0) { f1[wave] = a1; f2[wave] = a2; }
        __syncthreads();
        if (t == 0) {
            float sum_sq = f1[0] + f1[1] + f1[2] + f1[3];
            float sum3   = f2[0] + f2[1] + f2[2] + f2[3];
            float slog = 0.0f;
            #pragma unroll
            for (int i = 0; i < 64; ++i) slog += ws[WS_LOG + i];
            out[0] = ALPHA * sum_sq - (float)SDIM * slog
                   + sum3 * (1.0f / ((float)SDIM * (float)SDIM));
        }
        return;
    }

    // ---- writer role: rows n0, n1; only L2-hot reads (32 KB shared) ----
    int n0 = 2 * b, n1 = 2 * b + 1;
    const float* c1 = c0 + SDIM;
    const float4* u04 = (const float4*)(c0 + 3 * SDIM);
    const float4* u14 = (const float4*)(c0 + 4 * SDIM);

    float a00 = c0[n0], b00 = c1[n0];  // wave-uniform scalars
    float a01 = c0[n1], b01 = c1[n1];

    float4 U0[4], U1[4];
    #pragma unroll
    for (int k = 0; k < 4; ++k) {
        U0[k] = u04[k * 256 + t];
        U1[k] = u14[k * 256 + t];
    }

    nfloat4* orow0 = (nfloat4*)(out + (size_t)n0 * SDIM);
    nfloat4* orow1 = (nfloat4*)(out + (size_t)n1 * SDIM);
    #pragma unroll
    for (int k = 0; k < 4; ++k) {
        int j = k * 256 + t;
        float e0, e1;
        nfloat4 v0, v1;
        e0 = a00 - U0[k].x; e1 = b00 - U1[k].x; v0.x = 0.5f * (e0 * e0 + e1 * e1);
        e0 = a00 - U0[k].y; e1 = b00 - U1[k].y; v0.y = 0.5f * (e0 * e0 + e1 * e1);
        e0 = a00 - U0[k].z; e1 = b00 - U1[k].z; v0.z = 0.5f * (e0 * e0 + e1 * e1);
        e0 = a00 - U0[k].w; e1 = b00 - U1[k].w; v0.w = 0.5f * (e0 * e0 + e1 * e1);
        e0 = a01 - U0[k].x; e1 = b01 - U1[k].x; v1.x = 0.5f * (e0 * e0 + e1 * e1);
        e0 = a01 - U0[k].y; e1 = b01 - U1[k].y; v1.y = 0.5f * (e0 * e0 + e1 * e1);
        e0 = a01 - U0[k].z; e1 = b01 - U1[k].z; v1.z = 0.5f * (e0 * e0 + e1 * e1);
        e0 = a01 - U0[k].w; e1 = b01 - U1[k].w; v1.w = 0.5f * (e0 * e0 + e1 * e1);
        bool skipv0 = false;
        if (j == 0) {
            // element 0 of row-range n is cost[n-1][4095] (shifted layout)
            if (n0 == 0) {
                // out[0] is the loss slot, written ONLY by the finisher block.
                __builtin_nontemporal_store(v0.y, out + 1);
                __builtin_nontemporal_store(v0.z, out + 2);
                __builtin_nontemporal_store(v0.w, out + 3);
                skipv0 = true;
            } else {
                float ap = c0[n0 - 1], bp = c1[n0 - 1];
                e0 = ap - U0[0].x; e1 = bp - U1[0].x;   // U0[0].x = t0[4095]
                v0.x = 0.5f * (e0 * e0 + e1 * e1);
            }
            // n1 - 1 == n0
            e0 = a00 - U0[0].x; e1 = b00 - U1[0].x;
            v1.x = 0.5f * (e0 * e0 + e1 * e1);
        }
        if (!skipv0) __builtin_nontemporal_store(v0, &orow0[j]);
        __builtin_nontemporal_store(v1, &orow1[j]);
    }
    if (n1 == SDIM - 1 && t == 255) {
        // tail: out[16M] = cost[4095][4095]
        const float* u0 = c0 + 3 * SDIM;
        const float* u1 = c0 + 4 * SDIM;
        float e0 = a01 - u0[0], e1 = b01 - u1[0];  // u0[0] = t0[4095]
        out[(size_t)SDIM * SDIM] = 0.5f * (e0 * e0 + e1 * e1);
    }
}

extern "C" void kernel_launch(void* const* d_in, const int* in_sizes, int n_in,
                              void* d_out, int out_size, void* d_ws, size_t ws_size,
                              hipStream_t stream) {
    const float* inp = (const float*)d_in[0];
    const float* tgt = (const float*)d_in[1];
    float* out = (float*)d_out;
    float* ws  = (float*)d_ws;

    k_gather<<<64, 64, 0, stream>>>(inp, tgt, ws);
    k_reduce<<<NR, 256, 0, stream>>>(inp, tgt, ws, ws + WS_PART);
    k_writefin<<<NW + 1, 256, 0, stream>>>(ws, out);
}